// Round 2
// baseline (246.789 us; speedup 1.0000x reference)
//
#include <hip/hip_runtime.h>

// DualModeSinkhorn, N_STREAMS=2, SINKHORN_ITER=20.
// The scan body is linear per (b,h,w): row step x[i][j] -> -x[i][1-j],
// col step y[i][j] -> -y[1-i][j]; composed: x[i][j] -> x[1-i][1-j], an
// involution. 20 (even) iterations == identity, so output = exp(input)
// elementwise. Memory-bound: 302 MB traffic -> ~46 us floor at the
// fill-measured 6.7 TB/s ceiling.
//
// This version: grid-stride at 2048 blocks (256 CU x 8) + nontemporal
// 16B loads/stores (touch-once streams; skip cache allocation).
// Note: nontemporal builtins need a NATIVE clang vector type, not
// HIP_vector_type<float,4> — hence f32x4 below.

typedef float f32x4 __attribute__((ext_vector_type(4)));

__global__ void __launch_bounds__(256)
exp_vec4_gs_kernel(const f32x4* __restrict__ in, f32x4* __restrict__ out, int n4) {
    int stride = gridDim.x * blockDim.x;
    for (int idx = blockIdx.x * blockDim.x + threadIdx.x; idx < n4; idx += stride) {
        f32x4 v = __builtin_nontemporal_load(&in[idx]);
        f32x4 r;
        r.x = __expf(v.x);
        r.y = __expf(v.y);
        r.z = __expf(v.z);
        r.w = __expf(v.w);
        __builtin_nontemporal_store(r, &out[idx]);
    }
}

__global__ void __launch_bounds__(64)
exp_tail_kernel(const float* __restrict__ in, float* __restrict__ out,
                int start, int n) {
    int idx = start + blockIdx.x * blockDim.x + threadIdx.x;
    if (idx < n) {
        out[idx] = __expf(in[idx]);
    }
}

extern "C" void kernel_launch(void* const* d_in, const int* in_sizes, int n_in,
                              void* d_out, int out_size, void* d_ws, size_t ws_size,
                              hipStream_t stream) {
    const float* in = (const float*)d_in[0];
    float* out = (float*)d_out;
    int n = out_size;                 // == 16*4*768*768 = 37,748,736 (divisible by 4)
    int n4 = n / 4;

    if (n4 > 0) {
        int blocks = (n4 + 255) / 256;
        if (blocks > 2048) blocks = 2048;   // 256 CU x 8 wg/CU, grid-stride the rest
        exp_vec4_gs_kernel<<<blocks, 256, 0, stream>>>(
            (const f32x4*)in, (f32x4*)out, n4);
    }
    int rem = n - n4 * 4;
    if (rem > 0) {
        exp_tail_kernel<<<1, 64, 0, stream>>>(in, out, n4 * 4, n);
    }
}